// Round 13
// baseline (1396.057 us; speedup 1.0000x reference)
//
#include <hip/hip_runtime.h>
#include <math.h>

#define NM   50
#define NB   128
#define NL   3
#define NCLS 10

#define PI_D        3.14159265358979323846264338327950288
#define TWO_PI_D    6.28318530717958647692528676655900577
#define INV_2PI_D   0.159154943091895335768883763372514362
#define LAMBDA_D    5.32e-07
#define DIST_D      0.035
#define PLD_D       (PI_D * LAMBDA_D * DIST_D)

// Reference per layer: field = ifft2(fft2(field * e^{i phase}) * H),
// H = e^{ikD} * Hx[fx] * Hy[fy], ifft2 carries 1/4096. We drop e^{ikD}
// (global phase, killed by |.|^2) and the exact 2^-12 scales, folding
// 2^-72 * (1/NM) into one FC constant:
#define OUT_SCALE 4.2351647362715017e-24f   // (1/50) * 2^-72

typedef float f2 __attribute__((ext_vector_type(2)));

__device__ __forceinline__ f2 mkf2(float a, float b) { f2 r; r.x = a; r.y = b; return r; }

// Unified LDS swizzle (R4/R7-proven): element (r,c) at r*64 + (c ^ ((r&3)<<2) ^ ((c>>4)&3)).
__device__ __forceinline__ int sw(int r, int c) {
    return r * 64 + (c ^ (((r & 3) << 2) ^ ((c >> 4) & 3)));
}
// intensity-buffer swizzle (write natural-per-quad, read row-contiguous)
#define QS(r) ((((r) & 15)) << 1)

__device__ __forceinline__ constexpr int rev4(int i) {
    return ((i & 1) << 3) | ((i & 2) << 1) | ((i & 4) >> 1) | ((i & 8) >> 3);
}

__device__ __forceinline__ float dppx1(float v) {  // lane ^ 1 within quad
    return __int_as_float(__builtin_amdgcn_mov_dpp(__float_as_int(v), 0xB1, 0xF, 0xF, true));
}
__device__ __forceinline__ float dppx2(float v) {  // lane ^ 2 within quad
    return __int_as_float(__builtin_amdgcn_mov_dpp(__float_as_int(v), 0x4E, 0xF, 0xF, true));
}

// ---- complex primitives as f2 vector expressions (compiler forms VOP3P) ----
__device__ __forceinline__ f2 cmul(f2 a, f2 w) {          // a * w
    return a * w.x + a.yx * mkf2(-w.y, w.y);
}
__device__ __forceinline__ f2 cmulc(f2 a, f2 w) {         // a * conj(w)
    return a * w.x + a.yx * mkf2(w.y, -w.y);
}

__device__ __forceinline__ constexpr float c16t(int tw) {
    return (tw == 1) ? 0.923879532511286756f : (tw == 2) ? 0.707106781186547524f :
           (tw == 3) ? 0.382683432365089772f : (tw == 5) ? -0.382683432365089772f :
           (tw == 6) ? -0.707106781186547524f : (tw == 7) ? -0.923879532511286756f : 1.0f;
}
__device__ __forceinline__ constexpr float s16t(int tw) {
    return (tw == 1) ? 0.382683432365089772f : (tw == 2) ? 0.707106781186547524f :
           (tw == 3) ? 0.923879532511286756f : (tw == 5) ? 0.923879532511286756f :
           (tw == 6) ? 0.707106781186547524f : (tw == 7) ? 0.382683432365089772f : 0.0f;
}

// in-place DIF-16, natural in, bit-reversed out (pos i holds X[rev4(i)]), e^{-i}.
__device__ __forceinline__ void dif16_fwd(f2* x) {
#pragma unroll
    for (int len = 8; len >= 1; len >>= 1) {
#pragma unroll
        for (int base = 0; base < 16; base += 2 * len) {
#pragma unroll
            for (int j = 0; j < len; j++) {
                const int i0 = base + j, i1 = i0 + len;
                const int tw = j * (8 / len);
                f2 a = x[i0], b = x[i1];
                x[i0] = a + b;
                f2 d = a - b;
                if (tw == 0)      { x[i1] = d; }
                else if (tw == 4) { x[i1] = mkf2(d.y, -d.x); }              // * (-i)
                else {
                    const float c = c16t(tw), s = s16t(tw);
                    x[i1] = d * c + d.yx * mkf2(s, -s);
                }
            }
        }
    }
}

// in-place DIT-16, bit-reversed in, natural out, e^{+i}, unscaled.
__device__ __forceinline__ void dit16_inv(f2* x) {
#pragma unroll
    for (int len = 1; len <= 8; len <<= 1) {
#pragma unroll
        for (int base = 0; base < 16; base += 2 * len) {
#pragma unroll
            for (int j = 0; j < len; j++) {
                const int i0 = base + j, i1 = i0 + len;
                const int tw = j * (8 / len);
                f2 a = x[i0], b = x[i1];
                if (tw == 4)      { b = mkf2(-b.y, b.x); }                  // * (+i)
                else if (tw != 0) {
                    const float c = c16t(tw), s = s16t(tw);
                    b = b * c + b.yx * mkf2(-s, s);
                }
                x[i0] = a + b;
                x[i1] = a - b;
            }
        }
    }
}

// W64^{t*k} via register chain (R11-proven; no LDS, no loads).
template<int DIR>
__device__ __forceinline__ void twiddle_chain(f2* x, f2 w1) {
    f2 w = w1;
#pragma unroll
    for (int k = 1; k < 16; k++) {
        const int i = rev4(k);
        x[i] = (DIR > 0) ? cmulc(x[i], w) : cmul(x[i], w);
        if (k < 15) w = cmul(w, w1);
    }
}

// forward cross-quad 4-pt DFT: stage xor2, lane3 *(-i), stage xor1.
__device__ __forceinline__ void quad_fwd(f2* x, float s1, float s2, bool l3) {
#pragma unroll
    for (int i = 0; i < 16; i++) {
        f2 p = mkf2(dppx2(x[i].x), dppx2(x[i].y));
        f2 r = x[i] * s2 + p;
        f2 r2 = l3 ? mkf2(r.y, -r.x) : r;
        f2 q = mkf2(dppx1(r2.x), dppx1(r2.y));
        x[i] = r2 * s1 + q;
    }
}

// inverse cross-quad 4-pt DFT: stage xor1, lane3 *(+i), stage xor2 (unscaled).
__device__ __forceinline__ void quad_inv(f2* x, float s1, float s2, bool l3) {
#pragma unroll
    for (int i = 0; i < 16; i++) {
        f2 p = mkf2(dppx1(x[i].x), dppx1(x[i].y));
        f2 r = x[i] * s1 + p;
        f2 r2 = l3 ? mkf2(-r.y, r.x) : r;
        f2 q = mkf2(dppx2(r2.x), dppx2(r2.y));
        x[i] = r2 * s2 + q;
    }
}

// 64-pt forward: reg i, lane t -> X[rev4(i)+16*sig]
__device__ __forceinline__ void fwd64(f2* x, f2 w1, float s1, float s2, bool l3) {
    dif16_fwd(x);
    twiddle_chain<1>(x, w1);
    quad_fwd(x, s1, s2, l3);
}
__device__ __forceinline__ void inv64(f2* x, f2 w1, float s1, float s2, bool l3) {
    quad_inv(x, s1, s2, l3);
    twiddle_chain<-1>(x, w1);
    dit16_inv(x);
}

// H-multiply via 2-register quadratic chirp recurrence (R12-proven):
//   H[k+1] = H[k]*R[k],  R[k+1] = R[k]*C
__device__ __forceinline__ void hmul_chirp(f2* x, f2 H0, f2 R0, f2 C) {
    f2 H = H0, R = R0;
#pragma unroll
    for (int k = 0; k < 16; k++) {
        x[rev4(k)] = cmul(x[rev4(k)], H);
        if (k < 15) { H = cmul(H, R); R = cmul(R, C); }
    }
}

// ---------- pre-kernel: chirp seeds into d_ws (72 B, L1-hot) ----------
__global__ __launch_bounds__(64) void donn_tables(f2* __restrict__ ws)
{
    const int q = threadIdx.x;
    if (q < 4) {
        const double f0u = (q == 0) ? 0.0 : (q == 1) ? 16.0 : (q == 2) ? -32.0 : -16.0;
        const double D2 = 15625.0 * 15625.0;
        double ph0 = -PLD_D * f0u * f0u * D2;
        double r0  = -PLD_D * (2.0 * f0u + 1.0) * D2;
        ph0 -= TWO_PI_D * rint(ph0 * INV_2PI_D);
        r0  -= TWO_PI_D * rint(r0  * INV_2PI_D);
        ws[q]     = mkf2((float)cos(ph0), (float)sin(ph0));
        ws[4 + q] = mkf2((float)cos(r0),  (float)sin(r0));
        if (q == 0) {
            double c = -2.0 * PLD_D * D2;
            c -= TWO_PI_D * rint(c * INV_2PI_D);
            ws[8] = mkf2((float)cos(c), (float)sin(c));
        }
    }
}

// ---------- main kernel: LDS = 32768 exactly; VGPR capped for 5 waves/EU ----------
__global__ __launch_bounds__(256, 5) void donn_main(
    const float* __restrict__ x,
    const float* __restrict__ sre,
    const float* __restrict__ sim,
    const float* __restrict__ phase,
    const f2*    __restrict__ ws,
    const float* __restrict__ fcw,
    const float* __restrict__ fcb,
    float* __restrict__ out)
{
    __shared__ f2 xb2[4096];             // the ONLY LDS: 32 KiB -> 5-block cap

    const int tid = threadIdx.x;
    const int bid = blockIdx.x;
    const int b = bid & (NB - 1);
    const int m = bid >> 7;
    const int g = tid >> 2, t = tid & 3;
    const int sig = ((t & 1) << 1) | (t >> 1);
    const bool l3 = (t == 3);
    const float s1 = (t & 1) ? -1.f : 1.f;
    const float s2 = (t & 2) ? -1.f : 1.f;

    // per-thread base twiddle W64^t (reused by every fft64's register chain)
    float sw1, cw1;
    __sincosf((float)t * (float)(TWO_PI_D / 64.0), &sw1, &cw1);
    const f2 w1 = mkf2(cw1, sw1);

    // chirp seeds (6 persistent VGPRs; 3 b64 loads, 4/4/1 distinct addrs/wave)
    const f2 H0 = ws[sig];
    const f2 R0 = ws[4 + sig];
    const f2 Cc = ws[8];

    // stage field = x * screen straight into registers (cols 4j+t of row g)
    f2 X[16];
    {
        const float* xb = x   + b * 4096 + g * 64 + t;
        const float* sr = sre + m * 4096 + g * 64 + t;
        const float* si = sim + m * 4096 + g * 64 + t;
#pragma unroll
        for (int j = 0; j < 16; j++) {
            float xv = xb[4 * j];
            X[j].x = xv * sr[4 * j];
            X[j].y = xv * si[4 * j];
        }
    }
    // no initial barrier: no LDS tables, xb2 first touched by transpose #1

#pragma unroll 1
    for (int l = 0; l < NL; l++) {
        // multiply exp(i*phase_l) (natural order in regs)
        const float* ph = phase + l * 4096 + g * 64 + t;
#pragma unroll
        for (int j = 0; j < 16; j++) {
            float s, c;
            __sincosf(ph[4 * j], &s, &c);
            X[j] = cmul(X[j], mkf2(c, s));
        }
        // FFT along x, * Hx (chirp-generated)
        fwd64(X, w1, s1, s2, l3);
        hmul_chirp(X, H0, R0, Cc);
        // transpose #1 write (cells (g,kk) == own T2-read set of prev layer and
        // thread-unique -> no pre-barrier; b64 ops)
#pragma unroll
        for (int i = 0; i < 16; i++) {
            const int kk = rev4(i) + 16 * sig;
            xb2[sw(g, kk)] = X[i];
        }
        __syncthreads();
#pragma unroll
        for (int j = 0; j < 16; j++)
            X[j] = xb2[sw(4 * j + t, g)];
        // FFT along y, * Hx (== Hy up to global phase & folded scale),
        // inverse FFT along y -- all in regs
        fwd64(X, w1, s1, s2, l3);
        hmul_chirp(X, H0, R0, Cc);
        inv64(X, w1, s1, s2, l3);
        // transpose #2 write (cells (n,g) == own T1-read set -> no pre-barrier)
#pragma unroll
        for (int j = 0; j < 16; j++)
            xb2[sw(4 * j + t, g)] = X[j];
        __syncthreads();
#pragma unroll
        for (int i = 0; i < 16; i++) {
            const int kk = rev4(i) + 16 * sig;
            X[i] = xb2[sw(g, kk)];
        }
        // inverse FFT along x -> natural spatial order for next layer
        inv64(X, w1, s1, s2, l3);
    }

    // intensity -> float view of xb2 (QS layout). Barrier first: float rows
    // alias f2 rows that OTHER waves just T2-read.
    __syncthreads();
    float* xbf = (float*)xb2;
    const int qsg = QS(g);
#pragma unroll
    for (int j = 0; j < 16; j++) {
        const int c0 = 4 * j + t;
        xbf[g * 64 + (c0 ^ qsg)] = fmaf(X[j].x, X[j].x, X[j].y * X[j].y);
    }
    __syncthreads();   // pre-FC barrier (FC reads cross rows)

    float ivl[16];
#pragma unroll
    for (int i = 0; i < 16; i++) {
        const int e = i * 256 + tid;
        const int r = e >> 6, c = e & 63;
        ivl[i] = xbf[r * 64 + (c ^ QS(r))];
    }
    float part[NCLS];
#pragma unroll
    for (int c2 = 0; c2 < NCLS; c2++) part[c2] = 0.f;
#pragma unroll
    for (int c2 = 0; c2 < NCLS; c2++) {
        const float* wrow = fcw + c2 * 4096 + tid;
#pragma unroll
        for (int i = 0; i < 16; i++)
            part[c2] = fmaf(ivl[i], wrow[i * 256], part[c2]);
    }
#pragma unroll
    for (int c2 = 0; c2 < NCLS; c2++) {
        float v = part[c2];
#pragma unroll
        for (int off = 32; off >= 1; off >>= 1) v += __shfl_down(v, off);
        if ((tid & 63) == 0) atomicAdd(&out[b * NCLS + c2], v * OUT_SCALE);
    }
    if (m == 0 && tid < NCLS) atomicAdd(&out[b * NCLS + tid], fcb[tid]);
}

extern "C" void kernel_launch(void* const* d_in, const int* in_sizes, int n_in,
                              void* d_out, int out_size, void* d_ws, size_t ws_size,
                              hipStream_t stream) {
    const float* x   = (const float*)d_in[0];
    const float* sre = (const float*)d_in[1];
    const float* sim = (const float*)d_in[2];
    const float* ph  = (const float*)d_in[3];
    const float* fcw = (const float*)d_in[4];
    const float* fcb = (const float*)d_in[5];
    float* out = (float*)d_out;
    f2* ws = (f2*)d_ws;   // 9 f2: chirp seeds H0[4], R0[4], C

    hipMemsetAsync(out, 0, (size_t)(NB * NCLS) * sizeof(float), stream);
    donn_tables<<<1, 64, 0, stream>>>(ws);
    donn_main<<<NM * NB, 256, 0, stream>>>(x, sre, sim, ph, ws, fcw, fcb, out);
}

// Round 14
// 282.922 us; speedup vs baseline: 4.9344x; 4.9344x over previous
//
#include <hip/hip_runtime.h>
#include <math.h>

#define NM   50
#define NB   128
#define NL   3
#define NCLS 10

#define PI_D        3.14159265358979323846264338327950288
#define TWO_PI_D    6.28318530717958647692528676655900577
#define INV_2PI_D   0.159154943091895335768883763372514362
#define LAMBDA_D    5.32e-07
#define DIST_D      0.035
#define PLD_D       (PI_D * LAMBDA_D * DIST_D)

// Reference per layer: field = ifft2(fft2(field * e^{i phase}) * H),
// H = e^{ikD} * Hx[fx] * Hy[fy], ifft2 carries 1/4096. We drop e^{ikD}
// (global phase, killed by |.|^2) and the exact 2^-12 scales, folding
// 2^-72 * (1/NM) into one FC constant:
#define OUT_SCALE 4.2351647362715017e-24f   // (1/50) * 2^-72

typedef float f2 __attribute__((ext_vector_type(2)));

__device__ __forceinline__ f2 mkf2(float a, float b) { f2 r; r.x = a; r.y = b; return r; }

// Unified LDS swizzle (R4/R7-proven): element (r,c) at r*64 + (c ^ ((r&3)<<2) ^ ((c>>4)&3)).
__device__ __forceinline__ int sw(int r, int c) {
    return r * 64 + (c ^ (((r & 3) << 2) ^ ((c >> 4) & 3)));
}
// intensity-buffer swizzle (write natural-per-quad, read row-contiguous)
#define QS(r) ((((r) & 15)) << 1)

__device__ __forceinline__ constexpr int rev4(int i) {
    return ((i & 1) << 3) | ((i & 2) << 1) | ((i & 4) >> 1) | ((i & 8) >> 3);
}

__device__ __forceinline__ float dppx1(float v) {  // lane ^ 1 within quad
    return __int_as_float(__builtin_amdgcn_mov_dpp(__float_as_int(v), 0xB1, 0xF, 0xF, true));
}
__device__ __forceinline__ float dppx2(float v) {  // lane ^ 2 within quad
    return __int_as_float(__builtin_amdgcn_mov_dpp(__float_as_int(v), 0x4E, 0xF, 0xF, true));
}

// ---- complex primitives as f2 vector expressions (compiler forms VOP3P) ----
__device__ __forceinline__ f2 cmul(f2 a, f2 w) {          // a * w
    return a * w.x + a.yx * mkf2(-w.y, w.y);
}
__device__ __forceinline__ f2 cmulc(f2 a, f2 w) {         // a * conj(w)
    return a * w.x + a.yx * mkf2(w.y, -w.y);
}

__device__ __forceinline__ constexpr float c16t(int tw) {
    return (tw == 1) ? 0.923879532511286756f : (tw == 2) ? 0.707106781186547524f :
           (tw == 3) ? 0.382683432365089772f : (tw == 5) ? -0.382683432365089772f :
           (tw == 6) ? -0.707106781186547524f : (tw == 7) ? -0.923879532511286756f : 1.0f;
}
__device__ __forceinline__ constexpr float s16t(int tw) {
    return (tw == 1) ? 0.382683432365089772f : (tw == 2) ? 0.707106781186547524f :
           (tw == 3) ? 0.923879532511286756f : (tw == 5) ? 0.923879532511286756f :
           (tw == 6) ? 0.707106781186547524f : (tw == 7) ? 0.382683432365089772f : 0.0f;
}

// in-place DIF-16, natural in, bit-reversed out (pos i holds X[rev4(i)]), e^{-i}.
__device__ __forceinline__ void dif16_fwd(f2* x) {
#pragma unroll
    for (int len = 8; len >= 1; len >>= 1) {
#pragma unroll
        for (int base = 0; base < 16; base += 2 * len) {
#pragma unroll
            for (int j = 0; j < len; j++) {
                const int i0 = base + j, i1 = i0 + len;
                const int tw = j * (8 / len);
                f2 a = x[i0], b = x[i1];
                x[i0] = a + b;
                f2 d = a - b;
                if (tw == 0)      { x[i1] = d; }
                else if (tw == 4) { x[i1] = mkf2(d.y, -d.x); }              // * (-i)
                else {
                    const float c = c16t(tw), s = s16t(tw);
                    x[i1] = d * c + d.yx * mkf2(s, -s);
                }
            }
        }
    }
}

// in-place DIT-16, bit-reversed in, natural out, e^{+i}, unscaled.
__device__ __forceinline__ void dit16_inv(f2* x) {
#pragma unroll
    for (int len = 1; len <= 8; len <<= 1) {
#pragma unroll
        for (int base = 0; base < 16; base += 2 * len) {
#pragma unroll
            for (int j = 0; j < len; j++) {
                const int i0 = base + j, i1 = i0 + len;
                const int tw = j * (8 / len);
                f2 a = x[i0], b = x[i1];
                if (tw == 4)      { b = mkf2(-b.y, b.x); }                  // * (+i)
                else if (tw != 0) {
                    const float c = c16t(tw), s = s16t(tw);
                    b = b * c + b.yx * mkf2(-s, s);
                }
                x[i0] = a + b;
                x[i1] = a - b;
            }
        }
    }
}

// W64^{t*k} via register chain (R11-proven; no LDS, no loads).
template<int DIR>
__device__ __forceinline__ void twiddle_chain(f2* x, f2 w1) {
    f2 w = w1;
#pragma unroll
    for (int k = 1; k < 16; k++) {
        const int i = rev4(k);
        x[i] = (DIR > 0) ? cmulc(x[i], w) : cmul(x[i], w);
        if (k < 15) w = cmul(w, w1);
    }
}

// forward cross-quad 4-pt DFT: stage xor2, lane3 *(-i), stage xor1.
__device__ __forceinline__ void quad_fwd(f2* x, float s1, float s2, bool l3) {
#pragma unroll
    for (int i = 0; i < 16; i++) {
        f2 p = mkf2(dppx2(x[i].x), dppx2(x[i].y));
        f2 r = x[i] * s2 + p;
        f2 r2 = l3 ? mkf2(r.y, -r.x) : r;
        f2 q = mkf2(dppx1(r2.x), dppx1(r2.y));
        x[i] = r2 * s1 + q;
    }
}

// inverse cross-quad 4-pt DFT: stage xor1, lane3 *(+i), stage xor2 (unscaled).
__device__ __forceinline__ void quad_inv(f2* x, float s1, float s2, bool l3) {
#pragma unroll
    for (int i = 0; i < 16; i++) {
        f2 p = mkf2(dppx1(x[i].x), dppx1(x[i].y));
        f2 r = x[i] * s1 + p;
        f2 r2 = l3 ? mkf2(-r.y, r.x) : r;
        f2 q = mkf2(dppx2(r2.x), dppx2(r2.y));
        x[i] = r2 * s2 + q;
    }
}

// 64-pt forward: reg i, lane t -> X[rev4(i)+16*sig]
__device__ __forceinline__ void fwd64(f2* x, f2 w1, float s1, float s2, bool l3) {
    dif16_fwd(x);
    twiddle_chain<1>(x, w1);
    quad_fwd(x, s1, s2, l3);
}
__device__ __forceinline__ void inv64(f2* x, f2 w1, float s1, float s2, bool l3) {
    quad_inv(x, s1, s2, l3);
    twiddle_chain<-1>(x, w1);
    dit16_inv(x);
}

// H-multiply via 2-register quadratic chirp recurrence (R12-proven):
//   H[k+1] = H[k]*R[k],  R[k+1] = R[k]*C
__device__ __forceinline__ void hmul_chirp(f2* x, f2 H0, f2 R0, f2 C) {
    f2 H = H0, R = R0;
#pragma unroll
    for (int k = 0; k < 16; k++) {
        x[rev4(k)] = cmul(x[rev4(k)], H);
        if (k < 15) { H = cmul(H, R); R = cmul(R, C); }
    }
}

// ---------- pre-kernel: chirp seeds into d_ws (72 B, L1-hot) ----------
__global__ __launch_bounds__(64) void donn_tables(f2* __restrict__ ws)
{
    const int q = threadIdx.x;
    if (q < 4) {
        const double f0u = (q == 0) ? 0.0 : (q == 1) ? 16.0 : (q == 2) ? -32.0 : -16.0;
        const double D2 = 15625.0 * 15625.0;
        double ph0 = -PLD_D * f0u * f0u * D2;
        double r0  = -PLD_D * (2.0 * f0u + 1.0) * D2;
        ph0 -= TWO_PI_D * rint(ph0 * INV_2PI_D);
        r0  -= TWO_PI_D * rint(r0  * INV_2PI_D);
        ws[q]     = mkf2((float)cos(ph0), (float)sin(ph0));
        ws[4 + q] = mkf2((float)cos(r0),  (float)sin(r0));
        if (q == 0) {
            double c = -2.0 * PLD_D * D2;
            c -= TWO_PI_D * rint(c * INV_2PI_D);
            ws[8] = mkf2((float)cos(c), (float)sin(c));
        }
    }
}

// ---------- main kernel: LDS = 32768 exactly; natural regalloc (128) ----------
__global__ __launch_bounds__(256) void donn_main(
    const float* __restrict__ x,
    const float* __restrict__ sre,
    const float* __restrict__ sim,
    const float* __restrict__ phase,
    const f2*    __restrict__ ws,
    const float* __restrict__ fcw,
    const float* __restrict__ fcb,
    float* __restrict__ out)
{
    __shared__ f2 xb2[4096];             // the ONLY LDS: 32 KiB

    const int tid = threadIdx.x;
    const int bid = blockIdx.x;
    const int b = bid & (NB - 1);
    const int m = bid >> 7;
    const int g = tid >> 2, t = tid & 3;
    const int sig = ((t & 1) << 1) | (t >> 1);
    const bool l3 = (t == 3);
    const float s1 = (t & 1) ? -1.f : 1.f;
    const float s2 = (t & 2) ? -1.f : 1.f;

    // per-thread base twiddle W64^t (reused by every fft64's register chain)
    float sw1, cw1;
    __sincosf((float)t * (float)(TWO_PI_D / 64.0), &sw1, &cw1);
    const f2 w1 = mkf2(cw1, sw1);

    // chirp seeds (6 persistent VGPRs; 3 b64 loads, 4/4/1 distinct addrs/wave)
    const f2 H0 = ws[sig];
    const f2 R0 = ws[4 + sig];
    const f2 Cc = ws[8];

    // stage field = x * screen straight into registers (cols 4j+t of row g)
    f2 X[16];
    {
        const float* xb = x   + b * 4096 + g * 64 + t;
        const float* sr = sre + m * 4096 + g * 64 + t;
        const float* si = sim + m * 4096 + g * 64 + t;
#pragma unroll
        for (int j = 0; j < 16; j++) {
            float xv = xb[4 * j];
            X[j].x = xv * sr[4 * j];
            X[j].y = xv * si[4 * j];
        }
    }
    // no initial barrier: no LDS tables, xb2 first touched by transpose #1

#pragma unroll 1
    for (int l = 0; l < NL; l++) {
        // multiply exp(i*phase_l) (natural order in regs)
        const float* ph = phase + l * 4096 + g * 64 + t;
#pragma unroll
        for (int j = 0; j < 16; j++) {
            float s, c;
            __sincosf(ph[4 * j], &s, &c);
            X[j] = cmul(X[j], mkf2(c, s));
        }
        // FFT along x, * Hx (chirp-generated)
        fwd64(X, w1, s1, s2, l3);
        hmul_chirp(X, H0, R0, Cc);
        // transpose #1 write (cells (g,kk) == own T2-read set of prev layer and
        // thread-unique -> no pre-barrier; b64 ops)
#pragma unroll
        for (int i = 0; i < 16; i++) {
            const int kk = rev4(i) + 16 * sig;
            xb2[sw(g, kk)] = X[i];
        }
        __syncthreads();
#pragma unroll
        for (int j = 0; j < 16; j++)
            X[j] = xb2[sw(4 * j + t, g)];
        // FFT along y, * Hx (== Hy up to global phase & folded scale),
        // inverse FFT along y -- all in regs
        fwd64(X, w1, s1, s2, l3);
        hmul_chirp(X, H0, R0, Cc);
        inv64(X, w1, s1, s2, l3);
        // transpose #2 write (cells (n,g) == own T1-read set -> no pre-barrier)
#pragma unroll
        for (int j = 0; j < 16; j++)
            xb2[sw(4 * j + t, g)] = X[j];
        __syncthreads();
#pragma unroll
        for (int i = 0; i < 16; i++) {
            const int kk = rev4(i) + 16 * sig;
            X[i] = xb2[sw(g, kk)];
        }
        // inverse FFT along x -> natural spatial order for next layer
        inv64(X, w1, s1, s2, l3);
    }

    // intensity -> float view of xb2 (QS layout). Barrier first: float rows
    // alias f2 rows that OTHER waves just T2-read.
    __syncthreads();
    float* xbf = (float*)xb2;
    const int qsg = QS(g);
#pragma unroll
    for (int j = 0; j < 16; j++) {
        const int c0 = 4 * j + t;
        xbf[g * 64 + (c0 ^ qsg)] = fmaf(X[j].x, X[j].x, X[j].y * X[j].y);
    }
    __syncthreads();   // pre-FC barrier (FC reads cross rows)

    float ivl[16];
#pragma unroll
    for (int i = 0; i < 16; i++) {
        const int e = i * 256 + tid;
        const int r = e >> 6, c = e & 63;
        ivl[i] = xbf[r * 64 + (c ^ QS(r))];
    }
    float part[NCLS];
#pragma unroll
    for (int c2 = 0; c2 < NCLS; c2++) part[c2] = 0.f;
#pragma unroll
    for (int c2 = 0; c2 < NCLS; c2++) {
        const float* wrow = fcw + c2 * 4096 + tid;
#pragma unroll
        for (int i = 0; i < 16; i++)
            part[c2] = fmaf(ivl[i], wrow[i * 256], part[c2]);
    }
#pragma unroll
    for (int c2 = 0; c2 < NCLS; c2++) {
        float v = part[c2];
#pragma unroll
        for (int off = 32; off >= 1; off >>= 1) v += __shfl_down(v, off);
        if ((tid & 63) == 0) atomicAdd(&out[b * NCLS + c2], v * OUT_SCALE);
    }
    if (m == 0 && tid < NCLS) atomicAdd(&out[b * NCLS + tid], fcb[tid]);
}

extern "C" void kernel_launch(void* const* d_in, const int* in_sizes, int n_in,
                              void* d_out, int out_size, void* d_ws, size_t ws_size,
                              hipStream_t stream) {
    const float* x   = (const float*)d_in[0];
    const float* sre = (const float*)d_in[1];
    const float* sim = (const float*)d_in[2];
    const float* ph  = (const float*)d_in[3];
    const float* fcw = (const float*)d_in[4];
    const float* fcb = (const float*)d_in[5];
    float* out = (float*)d_out;
    f2* ws = (f2*)d_ws;   // 9 f2: chirp seeds H0[4], R0[4], C

    hipMemsetAsync(out, 0, (size_t)(NB * NCLS) * sizeof(float), stream);
    donn_tables<<<1, 64, 0, stream>>>(ws);
    donn_main<<<NM * NB, 256, 0, stream>>>(x, sre, sim, ph, ws, fcw, fcb, out);
}